// Round 4
// baseline (528.447 us; speedup 1.0000x reference)
//
#include <hip/hip_runtime.h>
#include <hip/hip_bf16.h>

#define B_     16
#define CIN_   512
#define COUT_  512
#define RES_   64
#define WDIM_  512
#define LRELU_A 0.2f
#define GAIN_  1.4142135623730951f

typedef __attribute__((ext_vector_type(8)))  __bf16 bf16x8;
typedef __attribute__((ext_vector_type(16))) float  f32x16;
typedef __attribute__((ext_vector_type(4)))  int    int4v;
typedef __attribute__((ext_vector_type(8)))  unsigned short u16x8;

__device__ __forceinline__ unsigned short f2bf(float f) {
    union { float f; unsigned int u; } v; v.f = f;
    unsigned int u = v.u;
    return (unsigned short)((u + 0x7FFFu + ((u >> 16) & 1u)) >> 16);  // RNE
}

// async global->LDS, 16B per lane; LDS dest = wave-uniform base + lane*16 (HW adds lane*16)
__device__ __forceinline__ void gl_lds16(const void* g, void* l) {
    __builtin_amdgcn_global_load_lds(
        (const __attribute__((address_space(1))) unsigned int*)g,
        (__attribute__((address_space(3))) unsigned int*)l, 16, 0, 0);
}

// ---------------- K0: zero halo rows (padded rows 0 and 65 of each b) -------------------
__global__ void zero_k(unsigned short* __restrict__ xs) {
    int idx = blockIdx.x * 256 + threadIdx.x;          // 131072 chunks of 16B
    int b = idx >> 13, side = (idx >> 12) & 1, off = idx & 4095;
    int4v z = {0, 0, 0, 0};
    *(int4v*)((char*)xs + ((size_t)(b * 66 + side * 65) * 4096 + off) * 16) = z;
}

// ---------------- K1: styles = w @ (affine_w^T / sqrt(512)) + affine_b ----------------
__global__ void styles_k(const float* __restrict__ w, const float* __restrict__ aw,
                         const float* __restrict__ ab, float* __restrict__ styles) {
    int idx = blockIdx.x * 256 + threadIdx.x;      // 8192 = b*512 + ci
    int b = idx >> 9, ci = idx & 511;
    const float4* wp = (const float4*)(w + b * WDIM_);
    const float4* ap = (const float4*)(aw + (size_t)ci * WDIM_);
    float acc = 0.f;
    #pragma unroll 4
    for (int k = 0; k < WDIM_ / 4; ++k) {
        float4 a = ap[k], q = wp[k];
        acc += a.x * q.x + a.y * q.y + a.z * q.z + a.w * q.w;
    }
    styles[idx] = acc * 0.04419417382415922f + ab[ci];   // 1/sqrt(512)
}

// ---------------- K2: wt_pack[cc][tap][co][ci16] bf16, wsq[co][ci] = sum_tap w^2 --------
__global__ void wprep_k(const float* __restrict__ weight, unsigned short* __restrict__ wt,
                        float* __restrict__ wsq) {
    int idx = blockIdx.x * 256 + threadIdx.x;      // 262144 = co*512 + ci
    int co = idx >> 9, ci = idx & 511;
    const float* wp = weight + (size_t)idx * 9;
    float s = 0.f;
    #pragma unroll
    for (int t = 0; t < 9; ++t) {
        float f = wp[t];
        s += f * f;
        wt[(((size_t)(ci >> 4) * 9 + t) * 512 + co) * 16 + (ci & 15)] = f2bf(f);
    }
    wsq[idx] = s;
}

// ---------------- K3: demod[b][co] = rsqrt(sum_ci wsq[co][ci]*styles[b][ci]^2 + 1e-8) ----
__global__ void demod_k(const float* __restrict__ styles, const float* __restrict__ wsq,
                        float* __restrict__ demod) {
    int idx = blockIdx.x * 256 + threadIdx.x;      // 8192 = b*512 + co
    int b = idx >> 9, co = idx & 511;
    const float4* wr = (const float4*)(wsq + (size_t)co * CIN_);
    const float4* sr = (const float4*)(styles + (size_t)b * CIN_);
    float acc = 0.f;
    #pragma unroll 4
    for (int ci = 0; ci < CIN_ / 4; ++ci) {
        float4 q = wr[ci], s = sr[ci];
        acc += q.x * s.x * s.x + q.y * s.y * s.y + q.z * s.z * s.z + q.w * s.w * s.w;
    }
    demod[idx] = rsqrtf(acc + 1e-8f);
}

// ------- K4: xs[b][h+1][cc][w][ci16] = bf16(x[b][ci][h][w] * styles[b][ci]) -------------
// grid 8192 = (b, h, ct): ct selects 64 ci. Coalesced float4 in, dense ushort8 out.
__global__ void xprep_k(const float* __restrict__ x, const float* __restrict__ styles,
                        unsigned short* __restrict__ xs) {
    __shared__ float tile[64][65];
    __shared__ float styv[64];
    int bid = blockIdx.x;
    int ct = bid & 7, h = (bid >> 3) & 63, b = bid >> 9;
    int tid = threadIdx.x;
    if (tid < 64) styv[tid] = styles[b * CIN_ + ct * 64 + tid];
    const float* xp = x + (((size_t)(b * CIN_ + ct * 64)) * RES_ + h) * RES_;
    #pragma unroll
    for (int it = 0; it < 4; ++it) {
        int ci = it * 16 + (tid >> 4);
        int w4 = (tid & 15) * 4;
        float4 v = *(const float4*)(xp + (size_t)ci * (RES_ * RES_) + w4);
        tile[ci][w4] = v.x; tile[ci][w4 + 1] = v.y; tile[ci][w4 + 2] = v.z; tile[ci][w4 + 3] = v.w;
    }
    __syncthreads();
    unsigned short* xo = xs + (size_t)(b * 66 + h + 1) * 32768 + (size_t)ct * 4096;
    #pragma unroll
    for (int it = 0; it < 2; ++it) {
        int s = it * 256 + tid;                // 0..511 chunk id -> contiguous 8-short runs
        int ccl = s >> 7, w = (s >> 1) & 63, half = s & 1;
        int ci0 = ccl * 16 + half * 8;
        u16x8 v;
        #pragma unroll
        for (int j = 0; j < 8; ++j) v[j] = f2bf(tile[ci0 + j][w] * styv[ci0 + j]);
        *(u16x8*)(xo + ccl * 1024 + w * 16 + half * 8) = v;
    }
}

// ---------------- K5: main conv. block: 128 co x 256 px (4 rows), 4 waves, CK=16 ---------
#define WBUF 36864                 // 9 taps * 128 co * 32B (single-buffered)
#define XBUF 12672                 // 6 rows * 132 chunks * 16B (double-buffered)
#define LDS_TOTAL (WBUF + 2*XBUF)  // 62208

__global__ __launch_bounds__(256, 2) void conv_k(
    const unsigned short* __restrict__ xs, const unsigned short* __restrict__ wt,
    const float* __restrict__ demod, const float* __restrict__ bias,
    const float* __restrict__ noise, const float* __restrict__ nsp,
    float* __restrict__ out)
{
    extern __shared__ char lds[];
    char* Wl = lds;                    // [WBUF]
    char* Xl = lds + WBUF;             // [2][XBUF]

    const int tid  = threadIdx.x;
    const int lane = tid & 63;
    const int wid  = tid >> 6;         // 0..3 = output row within block
    const int l31  = lane & 31;
    const int kg   = lane >> 5;

    // XCD swizzle: 1024 blocks; blocks on one XCD share the same W co-panel, rg inner
    const int lb = ((blockIdx.x & 7) << 7) | (blockIdx.x >> 3);
    const int m  = lb >> 8;            // 0..3 co-panel
    const int rest = lb & 255;
    const int b  = rest >> 4;
    const int h0 = (rest & 15) * 4;

    // zero column-halo chunks (chunks 0,1,130,131 of each of 6 rows, both X buffers).
    // Swizzle is identity on these chunk indices (bit3 clear), so reads see zeros.
    if (tid < 48) {
        int buf = tid / 24, rem = tid % 24, r = rem >> 2, k = rem & 3;
        int chunk = r * 132 + (k < 2 ? k : 128 + k);
        int4v z = {0, 0, 0, 0};
        *(int4v*)(Xl + buf * XBUF + chunk * 16) = z;
    }

    // ---- staging. LDS dest linear; SOURCE pre-permuted by the involution
    // sigma(c) = c ^ ((c>>3)&1) so that swizzled reads fetch the right data (rule #21).
    const char* wsrc = (const char*)wt + (size_t)m * (128 * 32);
    auto stageW = [&](int cc) {
        const char* s0 = wsrc + (size_t)cc * (9 * 512 * 32);
        #pragma unroll
        for (int k = 0; k < 9; ++k) {              // 9*256 = 2304 chunks exactly
            const int c0 = k * 256 + (wid << 6);   // wave-uniform
            const int c  = c0 + lane;
            const int sc = c ^ ((c >> 3) & 1);
            gl_lds16(s0 + (size_t)(sc >> 8) * 16384 + (size_t)(sc & 255) * 16,
                     Wl + c0 * 16);
        }
    };
    const char* xsrc = (const char*)xs + (size_t)(b * 66 + h0) * 65536;
    auto stageX = [&](int cc, int buf) {
        const char* s0 = xsrc + cc * 2048;         // [row][cc][w][ci16]
        char* d0 = Xl + buf * XBUF;
        #pragma unroll
        for (int k = 0; k < 3; ++k) {              // 3*256 = 768 chunks exactly
            const int c0 = k * 256 + (wid << 6);   // wave-uniform
            const int r  = c0 >> 7;                // row 0..5, uniform within wave
            const int cw = ((c0 + lane) & 127) + 2;      // dest chunk-in-row 2..129
            const int sw = cw ^ ((cw >> 3) & 1);         // involution
            gl_lds16(s0 + (size_t)r * 65536 + (size_t)(sw - 2) * 16,
                     d0 + (r * 132 + ((c0 & 127) + 2)) * 16);
        }
    };

    f32x16 acc[4][2];
    #pragma unroll
    for (int mt = 0; mt < 4; ++mt)
        #pragma unroll
        for (int nt = 0; nt < 2; ++nt)
            #pragma unroll
            for (int j = 0; j < 16; ++j) acc[mt][nt][j] = 0.f;

    stageW(0);
    stageX(0, 0);
    asm volatile("s_waitcnt vmcnt(0)" ::: "memory");
    __syncthreads();

    int xb = 0;
    for (int cc = 0; cc < 32; ++cc) {
        if (cc < 31) stageX(cc + 1, xb ^ 1);       // async into other X buf
        const char* Xb = Xl + xb * XBUF;
        #pragma unroll
        for (int t = 0; t < 9; ++t) {
            const int dy = t / 3, dx = t % 3;      // compile-time under unroll
            bf16x8 af[4], bv[2];
            #pragma unroll
            for (int mt = 0; mt < 4; ++mt) {
                int o = (mt * 32 + l31) * 32 + (kg << 4);
                o ^= (o >> 3) & 16;                // bank swizzle
                af[mt] = *(const bf16x8*)(Wl + t * 4096 + o);
            }
            #pragma unroll
            for (int nt = 0; nt < 2; ++nt) {
                int site = nt * 32 + l31 + dx;     // 0..65, halo pre-zeroed
                int o = site * 32 + (kg << 4);
                o ^= (o >> 3) & 16;                // bank swizzle
                bv[nt] = *(const bf16x8*)(Xb + (wid + dy) * 2112 + o);
            }
            #pragma unroll
            for (int mt = 0; mt < 4; ++mt)
                #pragma unroll
                for (int nt = 0; nt < 2; ++nt)
                    acc[mt][nt] = __builtin_amdgcn_mfma_f32_32x32x16_bf16(
                        af[mt], bv[nt], acc[mt][nt], 0, 0, 0);
        }
        if (cc < 31) {
            __builtin_amdgcn_sched_barrier(0);
            __builtin_amdgcn_s_barrier();          // #1: all waves done reading Wl
            stageW(cc + 1);                        // overwrite single W buffer
            asm volatile("s_waitcnt vmcnt(0)" ::: "memory");  // W(cc+1) and X(cc+1) landed
            __builtin_amdgcn_s_barrier();          // #2: staged data visible to all
            __builtin_amdgcn_sched_barrier(0);
        }
        xb ^= 1;
    }

    // epilogue: demod, noise, bias, lrelu*gain
    const float nsv = nsp[0];
    const int h = h0 + wid;
    const float* dm = demod + b * COUT_ + m * 128;
    float nz[2];
    nz[0] = noise[h * 64 + l31] * nsv;
    nz[1] = noise[h * 64 + 32 + l31] * nsv;
    #pragma unroll
    for (int mt = 0; mt < 4; ++mt) {
        #pragma unroll
        for (int j = 0; j < 16; ++j) {
            // C/D layout (verified m74/m101): col = lane&31, row = (j&3)+8*(j>>2)+4*kg
            int row = (j & 3) + 8 * (j >> 2) + 4 * kg;
            int co  = mt * 32 + row;
            float d  = dm[co];
            float bs = bias[m * 128 + co];
            #pragma unroll
            for (int nt = 0; nt < 2; ++nt) {
                float v = acc[mt][nt][j] * d + nz[nt] + bs;
                v = (v >= 0.f ? v : LRELU_A * v) * GAIN_;
                out[((size_t)(b * COUT_ + m * 128 + co) * RES_ + h) * RES_ + nt * 32 + l31] = v;
            }
        }
    }
}

extern "C" void kernel_launch(void* const* d_in, const int* in_sizes, int n_in,
                              void* d_out, int out_size, void* d_ws, size_t ws_size,
                              hipStream_t stream) {
    const float* x    = (const float*)d_in[0];
    const float* w    = (const float*)d_in[1];
    const float* wgt  = (const float*)d_in[2];
    const float* bias = (const float*)d_in[3];
    const float* aw   = (const float*)d_in[4];
    const float* ab   = (const float*)d_in[5];
    const float* noi  = (const float*)d_in[6];
    const float* ns   = (const float*)d_in[7];
    float* out = (float*)d_out;

    char* ws = (char*)d_ws;
    float* styles        = (float*)(ws);                        // 32 KB
    float* demod         = (float*)(ws + 32768);                // 32 KB
    float* wsq           = (float*)(ws + 65536);                // 1 MB
    unsigned short* wt   = (unsigned short*)(ws + 1114112);     // 4.72 MB  [cc][tap][co][ci16]
    unsigned short* xs   = (unsigned short*)(ws + 6291456);     // 69.2 MB  [b][66][cc][w][ci16]

    hipLaunchKernelGGL(zero_k,   dim3(512),  dim3(256), 0, stream, xs);
    hipLaunchKernelGGL(styles_k, dim3(32),   dim3(256), 0, stream, w, aw, ab, styles);
    hipLaunchKernelGGL(wprep_k,  dim3(1024), dim3(256), 0, stream, wgt, wt, wsq);
    hipLaunchKernelGGL(xprep_k,  dim3(8192), dim3(256), 0, stream, x, styles, xs);
    hipLaunchKernelGGL(demod_k,  dim3(32),   dim3(256), 0, stream, styles, wsq, demod);

    hipFuncSetAttribute((const void*)conv_k, hipFuncAttributeMaxDynamicSharedMemorySize, LDS_TOTAL);
    hipLaunchKernelGGL(conv_k, dim3(1024), dim3(256), LDS_TOTAL, stream,
                       xs, wt, demod, bias, noi, ns, out);
}